// Round 3
// baseline (437.629 us; speedup 1.0000x reference)
//
#include <hip/hip_runtime.h>

#define NTOK 4096
#define DIM 1024
#define NE 8

typedef __bf16 bf16x8 __attribute__((ext_vector_type(8)));
typedef float floatx4 __attribute__((ext_vector_type(4)));

__device__ __forceinline__ unsigned short f2bf(float f) {
  unsigned u = __float_as_uint(f);
  u = u + 0x7fffu + ((u >> 16) & 1u);
  return (unsigned short)(u >> 16);
}
__device__ __forceinline__ float bf2f(unsigned short h) {
  return __uint_as_float(((unsigned)h) << 16);
}

// ---------------- gating: one WAVE per token. logits, softmax, top-2, x->bf16 ----------
__global__ __launch_bounds__(256) void gate_kernel(
    const float* __restrict__ x, const float* __restrict__ gW,
    const float* __restrict__ gb, unsigned short* __restrict__ x_bf,
    float* __restrict__ gp_out, int2* __restrict__ tops,
    float* __restrict__ pairw)
{
  const int tid = threadIdx.x;
  const int lane = tid & 63;
  const int wid = tid >> 6;
  const int t = blockIdx.x * 4 + wid;

  float4 xv[4];
#pragma unroll
  for (int j = 0; j < 4; j++)
    xv[j] = ((const float4*)(x + (size_t)t * DIM))[lane + 64 * j];
#pragma unroll
  for (int j = 0; j < 4; j++) {
    ushort4 xb;
    xb.x = f2bf(xv[j].x); xb.y = f2bf(xv[j].y);
    xb.z = f2bf(xv[j].z); xb.w = f2bf(xv[j].w);
    ((ushort4*)(x_bf + (size_t)t * DIM))[lane + 64 * j] = xb;
  }

  float p[NE];
#pragma unroll
  for (int e = 0; e < NE; e++) {
    const float4* gwe = (const float4*)(gW + e * DIM);
    float s = 0.f;
#pragma unroll
    for (int j = 0; j < 4; j++) {
      float4 g = gwe[lane + 64 * j];
      s += xv[j].x * g.x + xv[j].y * g.y + xv[j].z * g.z + xv[j].w * g.w;
    }
    p[e] = s;
  }
#pragma unroll
  for (int e = 0; e < NE; e++) {
#pragma unroll
    for (int off = 32; off >= 1; off >>= 1) p[e] += __shfl_xor(p[e], off);
  }

  float m = -1e30f;
#pragma unroll
  for (int e = 0; e < NE; e++) { p[e] += gb[e]; m = fmaxf(m, p[e]); }
  float s = 0.f;
  float pr[NE];
#pragma unroll
  for (int e = 0; e < NE; e++) { pr[e] = __expf(p[e] - m); s += pr[e]; }
  float inv = 1.f / s;
#pragma unroll
  for (int e = 0; e < NE; e++) pr[e] *= inv;

  if (lane < NE) gp_out[(size_t)t * NE + lane] = pr[lane];

  if (lane == 0) {
    int i0 = 0;
#pragma unroll
    for (int e = 1; e < NE; e++) if (pr[e] > pr[i0]) i0 = e;
    int i1 = (i0 == 0) ? 1 : 0;
#pragma unroll
    for (int e = 0; e < NE; e++) if (e != i0 && pr[e] > pr[i1]) i1 = e;
    float d = __expf(pr[i1] - pr[i0]);
    float w0 = 1.f / (1.f + d);
    tops[t] = make_int2(i0, i1);
    pairw[t * 2] = w0;
    pairw[t * 2 + 1] = 1.f - w0;
  }
}

// ---------------- binning: wave-aggregated atomics (1 atomic / expert / wave) ----------
__global__ __launch_bounds__(256) void bin_kernel(
    const int2* __restrict__ tops, int* __restrict__ cnt,
    int* __restrict__ bucket)
{
  const int t = blockIdx.x * 256 + threadIdx.x;
  const int lane = threadIdx.x & 63;
  int2 ti = tops[t];
#pragma unroll
  for (int slot = 0; slot < 2; slot++) {
    int e = slot ? ti.y : ti.x;
#pragma unroll
    for (int ex = 0; ex < NE; ex++) {
      bool mine = (e == ex);
      unsigned long long mask = __ballot(mine);
      if (mask) {
        int leader = __ffsll((long long)mask) - 1;
        int total = __popcll(mask);
        int prefix = __popcll(mask & ((1ull << lane) - 1ull));
        int base = 0;
        if (lane == leader) base = atomicAdd(&cnt[ex], total);
        base = __shfl(base, leader);
        if (mine) bucket[ex * NTOK + base + prefix] = t * 2 + slot;
      }
    }
  }
}

// ---------------- flat tile schedule: slot -> (expert, local m-tile) ----------
__global__ void sched_kernel(const int* __restrict__ cnt,
                             int* __restrict__ sched, int* __restrict__ sched_n)
{
  if (threadIdx.x == 0 && blockIdx.x == 0) {
    int pos = 0;
    for (int e = 0; e < NE; e++) {
      int tiles = (cnt[e] + 127) >> 7;
      for (int i = 0; i < tiles; i++) sched[pos++] = (e << 16) | i;
    }
    *sched_n = pos;
  }
}

// ---------------- fp32 -> bf16 weight conversion ----------------
__global__ __launch_bounds__(256) void cvt_kernel(
    const float4* __restrict__ src, ushort4* __restrict__ dst)
{
  int i = blockIdx.x * 256 + threadIdx.x;
  float4 v = src[i];
  ushort4 o;
  o.x = f2bf(v.x); o.y = f2bf(v.y); o.z = f2bf(v.z); o.w = f2bf(v.w);
  dst[i] = o;
}

// ---------------- grouped expert GEMM, register-prefetch pipeline -----------------------
// 128x128 tile, BK=64, 16x16x32 bf16 MFMA, XOR-swizzled LDS (conflict-free).
// Pipeline: global->VGPR loads for tile k+1 issued before MFMA phase on tile k;
// ds_write after the post-compute barrier (vmcnt drain lands AFTER compute).
// MODE 0: A = x_bf gathered by token (pid>>1), out = relu(acc + b1) -> h[pid]
// MODE 1: A = h gathered by pid,               out = (acc + b2) * pairw[pid] -> o_pair[pid]
template <int MODE>
__global__ __launch_bounds__(256) void ffn_gemm(
    const unsigned short* __restrict__ A,
    const unsigned short* __restrict__ B,     // [E][DIM][DIM] bf16, row-major (out,in)
    const float* __restrict__ bias,           // [E][DIM]
    const int* __restrict__ cnt, const int* __restrict__ bucket,
    const float* __restrict__ pairw,
    const int* __restrict__ sched, const int* __restrict__ sched_n,
    unsigned short* __restrict__ Out)
{
  const int slot = blockIdx.y;
  if (slot >= *sched_n) return;
  const int se = sched[slot];
  const int e  = se >> 16;
  const int mt = se & 0xffff;
  const int nt = blockIdx.x;
  const int n_e = cnt[e];

  __shared__ unsigned short lda[128 * 64];
  __shared__ unsigned short ldb[128 * 64];
  __shared__ int toks[128];

  const int tid = threadIdx.x;
  const int lane = tid & 63;
  const int wid = tid >> 6;

  if (tid < 128) {
    int r = mt * 128 + tid;
    if (r >= n_e) r = n_e - 1;     // clamp: duplicate row, store-masked later
    toks[tid] = bucket[e * NTOK + r];
  }
  __syncthreads();

  // per-thread staging: 4 A-granules + 4 B-granules (16B each), rows g*8+(lane>>3)
  const unsigned short* aptr[4];
  const unsigned short* bptr[4];
  int lidx[4];
#pragma unroll
  for (int j = 0; j < 4; j++) {
    int g = wid * 4 + j;
    int row = g * 8 + (lane >> 3);
    int c = lane & 7;
    int pid = toks[row];
    int arow = (MODE == 0) ? (pid >> 1) : pid;
    aptr[j] = A + (size_t)arow * DIM + (c << 3);
    int brow = nt * 128 + row;
    bptr[j] = B + (size_t)e * DIM * DIM + (size_t)brow * DIM + (c << 3);
    lidx[j] = row * 64 + ((c ^ (row & 7)) << 3);   // XOR granule swizzle
  }

  uint4 ra[4], rb[4];
#pragma unroll
  for (int j = 0; j < 4; j++) {
    ra[j] = *(const uint4*)aptr[j];
    rb[j] = *(const uint4*)bptr[j];
  }

  floatx4 acc[4][4] = {};
  const int wm = (wid & 1) * 64;
  const int wn = (wid >> 1) * 64;
  const int quad = lane >> 4;
  const int cl = lane & 15;
  const int sw = cl & 7;          // row&7 for all fragment rows

  for (int k0 = 0; k0 < 16; k0++) {
    // stage regs -> LDS (per-lane scatter, swizzled)
#pragma unroll
    for (int j = 0; j < 4; j++) {
      *(uint4*)&lda[lidx[j]] = ra[j];
      *(uint4*)&ldb[lidx[j]] = rb[j];
    }
    __syncthreads();

    // issue next tile's global loads (consumed after the post-MFMA barrier)
    if (k0 < 15) {
#pragma unroll
      for (int j = 0; j < 4; j++) {
        aptr[j] += 64;
        bptr[j] += 64;
        ra[j] = *(const uint4*)aptr[j];
        rb[j] = *(const uint4*)bptr[j];
      }
    }

    // MFMA phase on current tile
#pragma unroll
    for (int kk = 0; kk < 64; kk += 32) {
      const int gb = (kk >> 3) + quad;          // granule index 0..7
      const int goff = ((gb ^ sw) << 3);
      bf16x8 af[4], bfr[4];
#pragma unroll
      for (int mi = 0; mi < 4; mi++)
        af[mi] = *(const bf16x8*)&lda[(wm + mi * 16 + cl) * 64 + goff];
#pragma unroll
      for (int ni = 0; ni < 4; ni++)
        bfr[ni] = *(const bf16x8*)&ldb[(wn + ni * 16 + cl) * 64 + goff];
#pragma unroll
      for (int mi = 0; mi < 4; mi++)
#pragma unroll
        for (int ni = 0; ni < 4; ni++)
          acc[mi][ni] = __builtin_amdgcn_mfma_f32_16x16x32_bf16(af[mi], bfr[ni], acc[mi][ni], 0, 0, 0);
    }
    if (k0 < 15) __syncthreads();   // readers done before next ds_write
  }

  // epilogue: C/D layout col=lane&15, row=(lane>>4)*4+reg  [m89-verified]
#pragma unroll
  for (int ni = 0; ni < 4; ni++) {
    int col = nt * 128 + wn + ni * 16 + cl;
    float bval = bias[e * DIM + col];
#pragma unroll
    for (int mi = 0; mi < 4; mi++) {
#pragma unroll
      for (int reg = 0; reg < 4; reg++) {
        int rl = wm + mi * 16 + quad * 4 + reg;
        int r = mt * 128 + rl;
        if (r < n_e) {
          int pid = toks[rl];
          float v = acc[mi][ni][reg] + bval;
          if (MODE == 0) v = fmaxf(v, 0.f);
          else v *= pairw[pid];
          Out[(size_t)pid * DIM + col] = f2bf(v);
        }
      }
    }
  }
}

// ---------------- combine: y[t] = o_pair[2t] + o_pair[2t+1] (weights pre-folded) --------
__global__ __launch_bounds__(256) void combine_kernel(
    const unsigned short* __restrict__ o, float* __restrict__ y)
{
  const int t = blockIdx.x;
  const int tid = threadIdx.x;
  ushort4 a = ((const ushort4*)(o + (size_t)t * 2 * DIM))[tid];
  ushort4 b = ((const ushort4*)(o + (size_t)t * 2 * DIM + DIM))[tid];
  float4 r;
  r.x = bf2f(a.x) + bf2f(b.x);
  r.y = bf2f(a.y) + bf2f(b.y);
  r.z = bf2f(a.z) + bf2f(b.z);
  r.w = bf2f(a.w) + bf2f(b.w);
  ((float4*)(y + (size_t)t * DIM))[tid] = r;
}

extern "C" void kernel_launch(void* const* d_in, const int* in_sizes, int n_in,
                              void* d_out, int out_size, void* d_ws, size_t ws_size,
                              hipStream_t stream) {
  const float* x  = (const float*)d_in[0];
  const float* gW = (const float*)d_in[1];
  const float* gb = (const float*)d_in[2];
  const float* w1 = (const float*)d_in[3];
  const float* b1 = (const float*)d_in[4];
  const float* w2 = (const float*)d_in[5];
  const float* b2 = (const float*)d_in[6];
  float* y  = (float*)d_out;
  float* gp = (float*)d_out + (size_t)NTOK * DIM;

  // ws layout (bytes):
  //  [0,8M)    x_bf (bf16)          -- dead after gemm1; o_pair aliases [0,16M)
  //  [8M,24M)  w1_bf                -- dead after gemm1
  //  [24M,40M) w2_bf
  //  [40M,56M) h (bf16, row=pid)
  //  [56M,...) cnt | bucket | pairw | tops | sched | sched_n
  char* ws = (char*)d_ws;
  unsigned short* x_bf   = (unsigned short*)(ws);
  unsigned short* w1_bf  = (unsigned short*)(ws + (size_t)(8u  << 20));
  unsigned short* w2_bf  = (unsigned short*)(ws + (size_t)(24u << 20));
  unsigned short* hbuf   = (unsigned short*)(ws + (size_t)(40u << 20));
  unsigned short* o_pair = (unsigned short*)(ws);   // alias, safe by kernel ordering
  char* tail = ws + (size_t)(56u << 20);
  int*   cnt     = (int*)(tail);
  int*   bucket  = (int*)(tail + 1024);
  float* pairw   = (float*)(tail + 1024 + NE * NTOK * 4);
  int2*  tops    = (int2*) (tail + 1024 + NE * NTOK * 4 + NTOK * 2 * 4);
  int*   sched   = (int*)  (tail + 1024 + NE * NTOK * 4 + NTOK * 2 * 4 + NTOK * 2 * 4);
  int*   sched_n = sched + 128;

  hipMemsetAsync(cnt, 0, NE * sizeof(int), stream);
  gate_kernel<<<NTOK / 4, 256, 0, stream>>>(x, gW, gb, x_bf, gp, tops, pairw);
  bin_kernel<<<NTOK / 256, 256, 0, stream>>>(tops, cnt, bucket);
  sched_kernel<<<1, 64, 0, stream>>>(cnt, sched, sched_n);
  const int cvt_blocks = (NE * DIM * DIM / 4) / 256;  // 8192
  cvt_kernel<<<cvt_blocks, 256, 0, stream>>>((const float4*)w1, (ushort4*)w1_bf);
  cvt_kernel<<<cvt_blocks, 256, 0, stream>>>((const float4*)w2, (ushort4*)w2_bf);
  dim3 gg(8, 72);  // (n-tiles 1024/128, flat m-tile slots <= 64+8)
  ffn_gemm<0><<<gg, 256, 0, stream>>>(x_bf,  w1_bf, b1, cnt, bucket, pairw, sched, sched_n, hbuf);
  ffn_gemm<1><<<gg, 256, 0, stream>>>(hbuf, w2_bf, b2, cnt, bucket, pairw, sched, sched_n, o_pair);
  combine_kernel<<<NTOK, 256, 0, stream>>>(o_pair, y);
}

// Round 4
// 284.833 us; speedup vs baseline: 1.5364x; 1.5364x over previous
//
#include <hip/hip_runtime.h>

#define NTOK 4096
#define DIM 1024
#define NE 8

typedef __bf16 bf16x8 __attribute__((ext_vector_type(8)));
typedef float floatx4 __attribute__((ext_vector_type(4)));

__device__ __forceinline__ unsigned short f2bf(float f) {
  unsigned u = __float_as_uint(f);
  u = u + 0x7fffu + ((u >> 16) & 1u);
  return (unsigned short)(u >> 16);
}
__device__ __forceinline__ float bf2f(unsigned short h) {
  return __uint_as_float(((unsigned)h) << 16);
}

__device__ __forceinline__ void gld_lds16(const unsigned short* g, unsigned short* l) {
  __builtin_amdgcn_global_load_lds(
      (const __attribute__((address_space(1))) void*)g,
      (__attribute__((address_space(3))) void*)l, 16, 0, 0);
}

// ---------------- gating: one WAVE per token. logits, softmax, top-2, x->bf16 ----------
__global__ __launch_bounds__(256) void gate_kernel(
    const float* __restrict__ x, const float* __restrict__ gW,
    const float* __restrict__ gb, unsigned short* __restrict__ x_bf,
    float* __restrict__ gp_out, int2* __restrict__ tops,
    float* __restrict__ pairw)
{
  const int tid = threadIdx.x;
  const int lane = tid & 63;
  const int wid = tid >> 6;
  const int t = blockIdx.x * 4 + wid;

  float4 xv[4];
#pragma unroll
  for (int j = 0; j < 4; j++)
    xv[j] = ((const float4*)(x + (size_t)t * DIM))[lane + 64 * j];
#pragma unroll
  for (int j = 0; j < 4; j++) {
    ushort4 xb;
    xb.x = f2bf(xv[j].x); xb.y = f2bf(xv[j].y);
    xb.z = f2bf(xv[j].z); xb.w = f2bf(xv[j].w);
    ((ushort4*)(x_bf + (size_t)t * DIM))[lane + 64 * j] = xb;
  }

  float p[NE];
#pragma unroll
  for (int e = 0; e < NE; e++) {
    const float4* gwe = (const float4*)(gW + e * DIM);
    float s = 0.f;
#pragma unroll
    for (int j = 0; j < 4; j++) {
      float4 g = gwe[lane + 64 * j];
      s += xv[j].x * g.x + xv[j].y * g.y + xv[j].z * g.z + xv[j].w * g.w;
    }
    p[e] = s;
  }
#pragma unroll
  for (int e = 0; e < NE; e++) {
#pragma unroll
    for (int off = 32; off >= 1; off >>= 1) p[e] += __shfl_xor(p[e], off);
  }

  float m = -1e30f;
#pragma unroll
  for (int e = 0; e < NE; e++) { p[e] += gb[e]; m = fmaxf(m, p[e]); }
  float s = 0.f;
  float pr[NE];
#pragma unroll
  for (int e = 0; e < NE; e++) { pr[e] = __expf(p[e] - m); s += pr[e]; }
  float inv = 1.f / s;
#pragma unroll
  for (int e = 0; e < NE; e++) pr[e] *= inv;

  if (lane < NE) gp_out[(size_t)t * NE + lane] = pr[lane];

  if (lane == 0) {
    int i0 = 0;
#pragma unroll
    for (int e = 1; e < NE; e++) if (pr[e] > pr[i0]) i0 = e;
    int i1 = (i0 == 0) ? 1 : 0;
#pragma unroll
    for (int e = 0; e < NE; e++) if (e != i0 && pr[e] > pr[i1]) i1 = e;
    float d = __expf(pr[i1] - pr[i0]);
    float w0 = 1.f / (1.f + d);
    tops[t] = make_int2(i0, i1);
    pairw[t * 2] = w0;
    pairw[t * 2 + 1] = 1.f - w0;
  }
}

// ---------------- binning: wave-aggregated atomics (1 atomic / expert / wave) ----------
__global__ __launch_bounds__(256) void bin_kernel(
    const int2* __restrict__ tops, int* __restrict__ cnt,
    int* __restrict__ bucket)
{
  const int t = blockIdx.x * 256 + threadIdx.x;
  const int lane = threadIdx.x & 63;
  int2 ti = tops[t];
#pragma unroll
  for (int slot = 0; slot < 2; slot++) {
    int e = slot ? ti.y : ti.x;
#pragma unroll
    for (int ex = 0; ex < NE; ex++) {
      bool mine = (e == ex);
      unsigned long long mask = __ballot(mine);
      if (mask) {
        int leader = __ffsll((long long)mask) - 1;
        int total = __popcll(mask);
        int prefix = __popcll(mask & ((1ull << lane) - 1ull));
        int base = 0;
        if (lane == leader) base = atomicAdd(&cnt[ex], total);
        base = __shfl(base, leader);
        if (mine) bucket[ex * NTOK + base + prefix] = t * 2 + slot;
      }
    }
  }
}

// ---------------- flat tile schedule: slot -> (expert, local m-tile) ----------
__global__ void sched_kernel(const int* __restrict__ cnt,
                             int* __restrict__ sched, int* __restrict__ sched_n)
{
  if (threadIdx.x == 0 && blockIdx.x == 0) {
    int pos = 0;
    for (int e = 0; e < NE; e++) {
      int tiles = (cnt[e] + 127) >> 7;
      for (int i = 0; i < tiles; i++) sched[pos++] = (e << 16) | i;
    }
    *sched_n = pos;
  }
}

// ---------------- fp32 -> bf16 weight conversion ----------------
__global__ __launch_bounds__(256) void cvt_kernel(
    const float4* __restrict__ src, ushort4* __restrict__ dst)
{
  int i = blockIdx.x * 256 + threadIdx.x;
  float4 v = src[i];
  ushort4 o;
  o.x = f2bf(v.x); o.y = f2bf(v.y); o.z = f2bf(v.z); o.w = f2bf(v.w);
  dst[i] = o;
}

// ---------------- grouped expert GEMM: global_load_lds + LDS double-buffer -------------
// 128x128 tile, BK=64, 16x16x32 bf16 MFMA.
// Source-side XOR swizzle: lane covering LDS slot (row, c) fetches global granule
// c^(row&7) -> swizzled LDS image, conflict-free fragment reads (R3-verified: 0 conflicts),
// coalescing intact (permutation within one 128B row segment).
// One barrier per iter: stage k+1 -> buf[1-cur]; compute buf[cur]; barrier (vmcnt drain
// lands AFTER compute -> staging latency hidden, unlike R2's issue-then-drain).
// MODE 0: A = x_bf gathered by token (pid>>1), out = relu(acc + b1) -> h[pid]
// MODE 1: A = h gathered by pid,               out = (acc + b2) * pairw[pid] -> o_pair[pid]
template <int MODE>
__global__ __launch_bounds__(256) void ffn_gemm(
    const unsigned short* __restrict__ A,
    const unsigned short* __restrict__ B,     // [E][DIM][DIM] bf16, row-major (out,in)
    const float* __restrict__ bias,           // [E][DIM]
    const int* __restrict__ cnt, const int* __restrict__ bucket,
    const float* __restrict__ pairw,
    const int* __restrict__ sched, const int* __restrict__ sched_n,
    unsigned short* __restrict__ Out)
{
  const int slot = blockIdx.y;
  if (slot >= *sched_n) return;
  const int se = sched[slot];
  const int e  = se >> 16;
  const int mt = se & 0xffff;
  const int nt = blockIdx.x;
  const int n_e = cnt[e];

  __shared__ unsigned short lda[2][128 * 64];   // 2 x 16 KB
  __shared__ unsigned short ldb[2][128 * 64];   // 2 x 16 KB  (total 64 KB exactly)

  const int tid = threadIdx.x;
  const int lane = tid & 63;
  const int wid = tid >> 6;

  // staging source addresses (per-lane global gather is legal; LDS side is
  // wave-uniform base + lane*16). group g covers tile rows g*8..g*8+7.
  const unsigned short* aptr[4];
  const unsigned short* bptr[4];
#pragma unroll
  for (int j = 0; j < 4; j++) {
    int g = wid * 4 + j;
    int row = g * 8 + (lane >> 3);
    int gran = (lane & 7) ^ (row & 7);          // source-side XOR swizzle
    int r = mt * 128 + row;
    if (r >= n_e) r = n_e - 1;                  // clamp: duplicate row, store-masked later
    int pid = bucket[e * NTOK + r];
    int arow = (MODE == 0) ? (pid >> 1) : pid;
    aptr[j] = A + (size_t)arow * DIM + (gran << 3);
    int brow = nt * 128 + row;
    bptr[j] = B + (size_t)e * DIM * DIM + (size_t)brow * DIM + (gran << 3);
  }

  // prologue: stage tile 0 into buffer 0
#pragma unroll
  for (int j = 0; j < 4; j++) {
    int g = wid * 4 + j;
    gld_lds16(aptr[j], &lda[0][g * 512]);
    gld_lds16(bptr[j], &ldb[0][g * 512]);
    aptr[j] += 64;
    bptr[j] += 64;
  }
  __syncthreads();

  floatx4 acc[4][4] = {};
  const int wm = (wid & 1) * 64;
  const int wn = (wid >> 1) * 64;
  const int quad = lane >> 4;
  const int cl = lane & 15;
  const int sw = cl & 7;                         // row&7 for all fragment rows

  for (int k0 = 0; k0 < 16; k0++) {
    const int cur = k0 & 1;
    // stage next tile into the other buffer (completes during compute below;
    // the compiler's vmcnt(0) drain sits at the post-compute barrier)
    if (k0 < 15) {
#pragma unroll
      for (int j = 0; j < 4; j++) {
        int g = wid * 4 + j;
        gld_lds16(aptr[j], &lda[1 - cur][g * 512]);
        gld_lds16(bptr[j], &ldb[1 - cur][g * 512]);
        aptr[j] += 64;
        bptr[j] += 64;
      }
    }

    // MFMA phase on current buffer
#pragma unroll
    for (int kk = 0; kk < 64; kk += 32) {
      const int gb = (kk >> 3) + quad;           // granule index 0..7
      const int goff = ((gb ^ sw) << 3);
      bf16x8 af[4], bfr[4];
#pragma unroll
      for (int mi = 0; mi < 4; mi++)
        af[mi] = *(const bf16x8*)&lda[cur][(wm + mi * 16 + cl) * 64 + goff];
#pragma unroll
      for (int ni = 0; ni < 4; ni++)
        bfr[ni] = *(const bf16x8*)&ldb[cur][(wn + ni * 16 + cl) * 64 + goff];
#pragma unroll
      for (int mi = 0; mi < 4; mi++)
#pragma unroll
        for (int ni = 0; ni < 4; ni++)
          acc[mi][ni] = __builtin_amdgcn_mfma_f32_16x16x32_bf16(af[mi], bfr[ni], acc[mi][ni], 0, 0, 0);
    }
    if (k0 < 15) __syncthreads();
  }

  // epilogue: C/D layout col=lane&15, row=(lane>>4)*4+reg  [m89-verified]
#pragma unroll
  for (int ni = 0; ni < 4; ni++) {
    int col = nt * 128 + wn + ni * 16 + cl;
    float bval = bias[e * DIM + col];
#pragma unroll
    for (int mi = 0; mi < 4; mi++) {
#pragma unroll
      for (int reg = 0; reg < 4; reg++) {
        int rl = wm + mi * 16 + quad * 4 + reg;
        int r = mt * 128 + rl;
        if (r < n_e) {
          int pid = bucket[e * NTOK + r];
          float v = acc[mi][ni][reg] + bval;
          if (MODE == 0) v = fmaxf(v, 0.f);
          else v *= pairw[pid];
          Out[(size_t)pid * DIM + col] = f2bf(v);
        }
      }
    }
  }
}

// ---------------- combine: y[t] = o_pair[2t] + o_pair[2t+1] (weights pre-folded) --------
__global__ __launch_bounds__(256) void combine_kernel(
    const unsigned short* __restrict__ o, float* __restrict__ y)
{
  const int t = blockIdx.x;
  const int tid = threadIdx.x;
  ushort4 a = ((const ushort4*)(o + (size_t)t * 2 * DIM))[tid];
  ushort4 b = ((const ushort4*)(o + (size_t)t * 2 * DIM + DIM))[tid];
  float4 r;
  r.x = bf2f(a.x) + bf2f(b.x);
  r.y = bf2f(a.y) + bf2f(b.y);
  r.z = bf2f(a.z) + bf2f(b.z);
  r.w = bf2f(a.w) + bf2f(b.w);
  ((float4*)(y + (size_t)t * DIM))[tid] = r;
}

extern "C" void kernel_launch(void* const* d_in, const int* in_sizes, int n_in,
                              void* d_out, int out_size, void* d_ws, size_t ws_size,
                              hipStream_t stream) {
  const float* x  = (const float*)d_in[0];
  const float* gW = (const float*)d_in[1];
  const float* gb = (const float*)d_in[2];
  const float* w1 = (const float*)d_in[3];
  const float* b1 = (const float*)d_in[4];
  const float* w2 = (const float*)d_in[5];
  const float* b2 = (const float*)d_in[6];
  float* y  = (float*)d_out;
  float* gp = (float*)d_out + (size_t)NTOK * DIM;

  // ws layout (bytes):
  //  [0,8M)    x_bf (bf16)          -- dead after gemm1; o_pair aliases [0,16M)
  //  [8M,24M)  w1_bf                -- dead after gemm1
  //  [24M,40M) w2_bf
  //  [40M,56M) h (bf16, row=pid)
  //  [56M,...) cnt | bucket | pairw | tops | sched | sched_n
  char* ws = (char*)d_ws;
  unsigned short* x_bf   = (unsigned short*)(ws);
  unsigned short* w1_bf  = (unsigned short*)(ws + (size_t)(8u  << 20));
  unsigned short* w2_bf  = (unsigned short*)(ws + (size_t)(24u << 20));
  unsigned short* hbuf   = (unsigned short*)(ws + (size_t)(40u << 20));
  unsigned short* o_pair = (unsigned short*)(ws);   // alias, safe by kernel ordering
  char* tail = ws + (size_t)(56u << 20);
  int*   cnt     = (int*)(tail);
  int*   bucket  = (int*)(tail + 1024);
  float* pairw   = (float*)(tail + 1024 + NE * NTOK * 4);
  int2*  tops    = (int2*) (tail + 1024 + NE * NTOK * 4 + NTOK * 2 * 4);
  int*   sched   = (int*)  (tail + 1024 + NE * NTOK * 4 + NTOK * 2 * 4 + NTOK * 2 * 4);
  int*   sched_n = sched + 128;

  hipMemsetAsync(cnt, 0, NE * sizeof(int), stream);
  gate_kernel<<<NTOK / 4, 256, 0, stream>>>(x, gW, gb, x_bf, gp, tops, pairw);
  bin_kernel<<<NTOK / 256, 256, 0, stream>>>(tops, cnt, bucket);
  sched_kernel<<<1, 64, 0, stream>>>(cnt, sched, sched_n);
  const int cvt_blocks = (NE * DIM * DIM / 4) / 256;  // 8192
  cvt_kernel<<<cvt_blocks, 256, 0, stream>>>((const float4*)w1, (ushort4*)w1_bf);
  cvt_kernel<<<cvt_blocks, 256, 0, stream>>>((const float4*)w2, (ushort4*)w2_bf);
  dim3 gg(8, 72);  // (n-tiles 1024/128, flat m-tile slots <= 64+8)
  ffn_gemm<0><<<gg, 256, 0, stream>>>(x_bf,  w1_bf, b1, cnt, bucket, pairw, sched, sched_n, hbuf);
  ffn_gemm<1><<<gg, 256, 0, stream>>>(hbuf, w2_bf, b2, cnt, bucket, pairw, sched, sched_n, o_pair);
  combine_kernel<<<NTOK, 256, 0, stream>>>(o_pair, y);
}

// Round 6
// 238.686 us; speedup vs baseline: 1.8335x; 1.1933x over previous
//
#include <hip/hip_runtime.h>

#define NTOK 4096
#define DIM 1024
#define NE 8
#define NPAIR (NTOK * 2)

typedef __bf16 bf16x8 __attribute__((ext_vector_type(8)));
typedef float floatx4 __attribute__((ext_vector_type(4)));

__device__ __forceinline__ unsigned short f2bf(float f) {
  unsigned u = __float_as_uint(f);
  u = u + 0x7fffu + ((u >> 16) & 1u);
  return (unsigned short)(u >> 16);
}
__device__ __forceinline__ float bf2f(unsigned short h) {
  return __uint_as_float(((unsigned)h) << 16);
}

__device__ __forceinline__ void gld_lds16(const unsigned short* g, unsigned short* l) {
  __builtin_amdgcn_global_load_lds(
      (const __attribute__((address_space(1))) void*)g,
      (__attribute__((address_space(3))) void*)l, 16, 0, 0);
}

// ---------------- gating: one WAVE per token; block 0 zeroes cnt/done ----------------
__global__ __launch_bounds__(256) void gate_kernel(
    const float* __restrict__ x, const float* __restrict__ gW,
    const float* __restrict__ gb,
    float* __restrict__ gp_out, int2* __restrict__ tops,
    float* __restrict__ pairw, int* __restrict__ cnt, int* __restrict__ done)
{
  const int tid = threadIdx.x;
  if (blockIdx.x == 0) {
    if (tid < NE) cnt[tid] = 0;
    if (tid == NE) *done = 0;
  }
  const int lane = tid & 63;
  const int wid = tid >> 6;
  const int t = blockIdx.x * 4 + wid;

  float4 xv[4];
#pragma unroll
  for (int j = 0; j < 4; j++)
    xv[j] = ((const float4*)(x + (size_t)t * DIM))[lane + 64 * j];

  float p[NE];
#pragma unroll
  for (int e = 0; e < NE; e++) {
    const float4* gwe = (const float4*)(gW + e * DIM);
    float s = 0.f;
#pragma unroll
    for (int j = 0; j < 4; j++) {
      float4 g = gwe[lane + 64 * j];
      s += xv[j].x * g.x + xv[j].y * g.y + xv[j].z * g.z + xv[j].w * g.w;
    }
    p[e] = s;
  }
#pragma unroll
  for (int e = 0; e < NE; e++) {
#pragma unroll
    for (int off = 32; off >= 1; off >>= 1) p[e] += __shfl_xor(p[e], off);
  }

  float m = -1e30f;
#pragma unroll
  for (int e = 0; e < NE; e++) { p[e] += gb[e]; m = fmaxf(m, p[e]); }
  float s = 0.f;
  float pr[NE];
#pragma unroll
  for (int e = 0; e < NE; e++) { pr[e] = __expf(p[e] - m); s += pr[e]; }
  float inv = 1.f / s;
#pragma unroll
  for (int e = 0; e < NE; e++) pr[e] *= inv;

  if (lane < NE) gp_out[(size_t)t * NE + lane] = pr[lane];

  if (lane == 0) {
    int i0 = 0;
#pragma unroll
    for (int e = 1; e < NE; e++) if (pr[e] > pr[i0]) i0 = e;
    int i1 = (i0 == 0) ? 1 : 0;
#pragma unroll
    for (int e = 0; e < NE; e++) if (e != i0 && pr[e] > pr[i1]) i1 = e;
    float d = __expf(pr[i1] - pr[i0]);
    float w0 = 1.f / (1.f + d);
    tops[t] = make_int2(i0, i1);
    pairw[t * 2] = w0;
    pairw[t * 2 + 1] = 1.f - w0;
  }
}

// ------- binning + schedule: wave-aggregated atomics; last block builds sched ----------
__global__ __launch_bounds__(256) void bin_sched_kernel(
    const int2* __restrict__ tops, int* __restrict__ cnt,
    int* __restrict__ bucket,      // [NE][NTOK]: pair id per within-expert index
    int* __restrict__ posmap,      // [NPAIR]: (e<<16)|idx for each (token,slot)
    int* __restrict__ done, int* __restrict__ base,   // base[9]
    int* __restrict__ sched, int* __restrict__ sched_n)
{
  const int t = blockIdx.x * 256 + threadIdx.x;
  const int lane = threadIdx.x & 63;
  int2 ti = tops[t];
#pragma unroll
  for (int slot = 0; slot < 2; slot++) {
    int e = slot ? ti.y : ti.x;
#pragma unroll
    for (int ex = 0; ex < NE; ex++) {
      bool mine = (e == ex);
      unsigned long long mask = __ballot(mine);
      if (mask) {
        int leader = __ffsll((long long)mask) - 1;
        int total = __popcll(mask);
        int prefix = __popcll(mask & ((1ull << lane) - 1ull));
        int idx = 0;
        if (lane == leader) idx = atomicAdd(&cnt[ex], total);
        idx = __shfl(idx, leader) + prefix;
        if (mine) {
          bucket[ex * NTOK + idx] = t * 2 + slot;
          posmap[t * 2 + slot] = (ex << 16) | idx;
        }
      }
    }
  }
  __syncthreads();
  if (threadIdx.x == 0) {
    if (atomicAdd(done, 1) == gridDim.x - 1) {   // last block: build schedule
      int b = 0, pos = 0;
      for (int e = 0; e < NE; e++) {
        int c = atomicAdd(&cnt[e], 0);           // device-coherent read
        base[e] = b;
        int tiles = (c + 127) >> 7;
        for (int i = 0; i < tiles; i++) {
          int valid = c - i * 128; if (valid > 128) valid = 128;
          sched[pos++] = (e << 20) | (i << 8) | valid;
        }
        b += c;
      }
      base[NE] = b;
      *sched_n = pos;
    }
  }
}

// ---------------- fp32 -> bf16 weight conversion (one tensor per launch) ---------------
__global__ __launch_bounds__(256) void cvt_kernel(
    const float4* __restrict__ src, ushort4* __restrict__ dst)
{
  const int i = blockIdx.x * 256 + threadIdx.x;
  float4 v = src[i];
  ushort4 o;
  o.x = f2bf(v.x); o.y = f2bf(v.y); o.z = f2bf(v.z); o.w = f2bf(v.w);
  dst[i] = o;
}

// ---------------- pack tokens: A_pack[p] = bf16(x[token(p)]) ---------------------------
__global__ __launch_bounds__(256) void gather_kernel(
    const float* __restrict__ x, const int* __restrict__ bucket,
    const int* __restrict__ base, unsigned short* __restrict__ A_pack)
{
  const int p = blockIdx.x;
  int e = 0;
#pragma unroll
  for (int k = 0; k < NE - 1; k++) if (p >= base[k + 1]) e = k + 1;
  const int pair = bucket[e * NTOK + (p - base[e])];
  const int tok = pair >> 1;
  const int tid = threadIdx.x;
  float4 v = ((const float4*)(x + (size_t)tok * DIM))[tid];
  ushort4 o;
  o.x = f2bf(v.x); o.y = f2bf(v.y); o.z = f2bf(v.z); o.w = f2bf(v.w);
  ((ushort4*)(A_pack + (size_t)p * DIM))[tid] = o;
}

// ---------------- packed grouped GEMM: 128x128, BK=64, single-buffer, XOR swizzle ------
// A and Out are packed by expert (sequential rows). XCD-grouped mapping: all 8 n-tiles
// of a slot share one XCD's L2 (A dup=1). RELU=1: h=relu(acc+bias); RELU=0: acc+bias.
template <int RELU>
__global__ __launch_bounds__(256) void ffn_gemm(
    const unsigned short* __restrict__ A,     // packed [NPAIR][DIM]
    const unsigned short* __restrict__ B,     // [NE][DIM][DIM]
    const float* __restrict__ bias,           // [NE][DIM]
    const int* __restrict__ base,
    const int* __restrict__ sched, const int* __restrict__ sched_n,
    unsigned short* __restrict__ Out)         // packed
{
  const int l = blockIdx.x;
  const int xcd = l & 7;
  const int w = l >> 3;
  const int nt = w & 7;
  const int slot = xcd * 9 + (w >> 3);
  if (slot >= *sched_n) return;
  const int se = sched[slot];
  const int e = se >> 20;
  const int mt = (se >> 8) & 0xfff;
  const int valid = se & 255;               // valid rows in this tile (1..128)
  const int arow0 = base[e] + mt * 128;

  __shared__ unsigned short lda[128 * 64];  // 16 KB
  __shared__ unsigned short ldb[128 * 64];  // 16 KB (32 KB total -> 5 blocks/CU)

  const int tid = threadIdx.x;
  const int lane = tid & 63;
  const int wid = tid >> 6;

  const unsigned short* ap[4];
  const unsigned short* bp[4];
#pragma unroll
  for (int j = 0; j < 4; j++) {
    int g = wid * 4 + j;
    int row = g * 8 + (lane >> 3);
    int gran = (lane & 7) ^ (row & 7);      // source-side XOR swizzle (R3/R4: 0 conflicts)
    int prow = arow0 + row;                  // clamp pad rows in-bounds (masked at store)
    if (prow > NPAIR - 1) prow = NPAIR - 1;
    ap[j] = A + (size_t)prow * DIM + (gran << 3);
    bp[j] = B + ((size_t)e * DIM + nt * 128 + row) * DIM + (gran << 3);
  }

  floatx4 acc[4][4] = {};
  const int wm = (wid & 1) * 64;
  const int wn = (wid >> 1) * 64;
  const int quad = lane >> 4;
  const int cl = lane & 15;
  const int sw = cl & 7;

  for (int k0 = 0; k0 < 16; k0++) {
#pragma unroll
    for (int j = 0; j < 4; j++) {
      int g = wid * 4 + j;
      gld_lds16(ap[j], &lda[g * 512]);
      gld_lds16(bp[j], &ldb[g * 512]);
      ap[j] += 64;
      bp[j] += 64;
    }
    __syncthreads();
#pragma unroll
    for (int kk = 0; kk < 64; kk += 32) {
      const int gb = (kk >> 3) + quad;
      const int goff = ((gb ^ sw) << 3);
      bf16x8 af[4], bfr[4];
#pragma unroll
      for (int mi = 0; mi < 4; mi++)
        af[mi] = *(const bf16x8*)&lda[(wm + mi * 16 + cl) * 64 + goff];
#pragma unroll
      for (int ni = 0; ni < 4; ni++)
        bfr[ni] = *(const bf16x8*)&ldb[(wn + ni * 16 + cl) * 64 + goff];
#pragma unroll
      for (int mi = 0; mi < 4; mi++)
#pragma unroll
        for (int ni = 0; ni < 4; ni++)
          acc[mi][ni] = __builtin_amdgcn_mfma_f32_16x16x32_bf16(af[mi], bfr[ni], acc[mi][ni], 0, 0, 0);
    }
    if (k0 < 15) __syncthreads();
  }

  // epilogue: C/D layout col=lane&15, row=(lane>>4)*4+reg [m89]; sequential packed store
#pragma unroll
  for (int ni = 0; ni < 4; ni++) {
    int col = nt * 128 + wn + ni * 16 + cl;
    float bval = bias[e * DIM + col];
#pragma unroll
    for (int mi = 0; mi < 4; mi++) {
#pragma unroll
      for (int reg = 0; reg < 4; reg++) {
        int rl = wm + mi * 16 + quad * 4 + reg;
        if (rl < valid) {
          float v = acc[mi][ni][reg] + bval;
          if (RELU) v = fmaxf(v, 0.f);
          Out[(size_t)(arow0 + rl) * DIM + col] = f2bf(v);
        }
      }
    }
  }
}

// ---------------- combine: y[t] = w0*o[p0] + w1*o[p1] (gather via posmap) --------------
__global__ __launch_bounds__(256) void combine_kernel(
    const unsigned short* __restrict__ o, const int* __restrict__ posmap,
    const int* __restrict__ base, const float* __restrict__ pairw,
    float* __restrict__ y)
{
  const int t = blockIdx.x;
  const int tid = threadIdx.x;
  const int pm0 = posmap[t * 2], pm1 = posmap[t * 2 + 1];
  const int p0 = base[pm0 >> 16] + (pm0 & 0xffff);
  const int p1 = base[pm1 >> 16] + (pm1 & 0xffff);
  const float w0 = pairw[t * 2], w1 = pairw[t * 2 + 1];
  ushort4 a = ((const ushort4*)(o + (size_t)p0 * DIM))[tid];
  ushort4 b = ((const ushort4*)(o + (size_t)p1 * DIM))[tid];
  float4 r;
  r.x = w0 * bf2f(a.x) + w1 * bf2f(b.x);
  r.y = w0 * bf2f(a.y) + w1 * bf2f(b.y);
  r.z = w0 * bf2f(a.z) + w1 * bf2f(b.z);
  r.w = w0 * bf2f(a.w) + w1 * bf2f(b.w);
  ((float4*)(y + (size_t)t * DIM))[tid] = r;
}

extern "C" void kernel_launch(void* const* d_in, const int* in_sizes, int n_in,
                              void* d_out, int out_size, void* d_ws, size_t ws_size,
                              hipStream_t stream) {
  const float* x  = (const float*)d_in[0];
  const float* gW = (const float*)d_in[1];
  const float* gb = (const float*)d_in[2];
  const float* w1 = (const float*)d_in[3];
  const float* b1 = (const float*)d_in[4];
  const float* w2 = (const float*)d_in[5];
  const float* b2 = (const float*)d_in[6];
  float* y  = (float*)d_out;
  float* gp = (float*)d_out + (size_t)NTOK * DIM;

  // ws layout (bytes) — peak 48M + ~230K, inside the 56.4M envelope validated R1-R4.
  // Staged aliasing (all kernels in-stream sequential):
  //  region0 [0,16M):   A_pack (gemm1 A)  -> dead after gemm1 -> w2_bf (cvt after gemm1)
  //  region1 [16,32M):  h_pack
  //  region2 [32,48M):  w1_bf (gemm1 B)   -> dead after gemm1 -> o_pack (gemm2 out)
  //  [48M,..):  cnt|done|base|sched|sched_n|bucket|pairw|tops|posmap
  char* ws = (char*)d_ws;
  unsigned short* A_pack = (unsigned short*)(ws);
  unsigned short* w2_bf  = (unsigned short*)(ws);                      // alias, post-gemm1
  unsigned short* h_pack = (unsigned short*)(ws + (size_t)(16u << 20));
  unsigned short* w1_bf  = (unsigned short*)(ws + (size_t)(32u << 20));
  unsigned short* o_pack = (unsigned short*)(ws + (size_t)(32u << 20)); // alias, post-gemm1
  char* tail = ws + (size_t)(48u << 20);
  int*   cnt     = (int*)(tail);                   // 8
  int*   done    = cnt + NE;                       // 1
  int*   base    = done + 1;                       // 9
  int*   sched   = base + NE + 1;                  // <=128
  int*   sched_n = sched + 128;                    // 1
  int*   bucket  = sched_n + 1;                    // NE*NTOK
  float* pairw   = (float*)(bucket + NE * NTOK);   // NPAIR
  int2*  tops    = (int2*)(pairw + NPAIR);         // NTOK
  int*   posmap  = (int*)(tops + NTOK);            // NPAIR

  const int cvt_blocks = (NE * DIM * DIM / 4) / 256;  // 8192
  gate_kernel<<<NTOK / 4, 256, 0, stream>>>(x, gW, gb, gp, tops, pairw, cnt, done);
  bin_sched_kernel<<<NTOK / 256, 256, 0, stream>>>(tops, cnt, bucket, posmap, done,
                                                   base, sched, sched_n);
  cvt_kernel<<<cvt_blocks, 256, 0, stream>>>((const float4*)w1, (ushort4*)w1_bf);
  gather_kernel<<<NPAIR, 256, 0, stream>>>(x, bucket, base, A_pack);
  ffn_gemm<1><<<576, 256, 0, stream>>>(A_pack, w1_bf, b1, base, sched, sched_n, h_pack);
  cvt_kernel<<<cvt_blocks, 256, 0, stream>>>((const float4*)w2, (ushort4*)w2_bf);
  ffn_gemm<0><<<576, 256, 0, stream>>>(h_pack, w2_bf, b2, base, sched, sched_n, o_pack);
  combine_kernel<<<NTOK, 256, 0, stream>>>(o_pack, posmap, base, pairw, y);
}